// Round 14
// baseline (172.952 us; speedup 1.0000x reference)
//
#include <hip/hip_runtime.h>
#include <hip/hip_bf16.h>
#include <math.h>

#define C 8
#define K 128
#define S 64
#define L 2048
#define NB 64
#define W (L - S + 1)   // 1985
#define TW 128
#define NTW 16
#define XCS 208         // xcop stride shorts: 104 dw = 8 banks mod 32 -> conflict-free b128
#define XFS 200         // fp32 x scratch stride (192 data + 8 zero pad)

typedef __attribute__((ext_vector_type(8))) short bf16x8;
typedef __attribute__((ext_vector_type(4))) float f32x4;

__device__ __forceinline__ unsigned short f2bf(float f) {
  unsigned int u = __float_as_uint(f);
  u += 0x7FFFu + ((u >> 16) & 1u);   // RNE
  return (unsigned short)(u >> 16);
}

// packed f32x2 -> bf16x2 (v_cvt_pk_bf16_f32 on gfx950)
__device__ __forceinline__ unsigned int pkbf(float a, float b) {
  __hip_bfloat162 h = __float22bfloat162_rn(make_float2(a, b));
  return *reinterpret_cast<unsigned int*>(&h);
}

// full-wave ONLY (R8 lesson: lane-predicated global_load_lds explodes traffic)
__device__ __forceinline__ void gll16(const void* g, void* l) {
  __builtin_amdgcn_global_load_lds((const __attribute__((address_space(1))) void*)g,
                                   (__attribute__((address_space(3))) void*)l, 16, 0, 0);
}

// prep: z-normalize shapelets -> bf16 * (-2) in B-fragment order, 16 KB per
// channel contiguous; init out to +inf. sum(z^2) == 64 exactly -> no sqs.
__global__ __launch_bounds__(256) void prep_kernel(const float* __restrict__ sh,
                                                   unsigned short* __restrict__ shzB,
                                                   float* __restrict__ out) {
  int tid = blockIdx.x * 256 + threadIdx.x;
  if (tid < NB * K) out[tid] = __int_as_float(0x7F800000);
  int gid = blockIdx.x * 4 + (threadIdx.x >> 6);  // c*K + k
  int lane = threadIdx.x & 63;                    // = s
  float v = sh[(size_t)gid * S + lane];
  float s1 = v, s2 = v * v;
#pragma unroll
  for (int off = 32; off > 0; off >>= 1) {
    s1 += __shfl_down(s1, off);
    s2 += __shfl_down(s2, off);
  }
  s1 = __shfl(s1, 0);
  s2 = __shfl(s2, 0);
  float mu = s1 * (1.0f / S);
  float sd = sqrtf(fmaxf(s2 * (1.0f / S) - mu * mu, 0.0f));
  float z = (v - mu) / sd;
  int c = gid >> 7, k = gid & (K - 1), s = lane;
  // B-frag layout: [c][k>>4][s>>5][lane'=((s>>3)&3)*16+(k&15)][s&7]
  int idx = c * 8192 + ((k >> 4) * 2 + (s >> 5)) * 512 +
            ((((s >> 3) & 3) * 16 + (k & 15)) * 8) + (s & 7);
  shzB[idx] = f2bf(-2.0f * z);   // bake the -2 of d2 = (sqx + 64) - 2*cross
}

// main: block = 128w x 128k, 512 threads = 8 waves, wave tile 64w x 32k
// (8 LDS-bytes per output-channel vs R13's 14 -- the measured binder).
// R13's proven structure: single 16 KB B buffer, per channel:
//   [READY] -> 4 B ds_reads -> [DONE] -> prefetch B[c+1] -> acc+MFMA+epilogue
// LDS 46 KB -> 3 blocks/CU. Accumulators never cross a barrier.
__global__ __launch_bounds__(512) void main_kernel(const float* __restrict__ x,
                                                   const unsigned short* __restrict__ shzB,
                                                   int* __restrict__ out) {
  __shared__ __align__(16) unsigned short bbuf[8192];      // 16 KB: B[c], full K
  __shared__ __align__(16) unsigned short xcop[C][8][XCS]; // 26 KB: 8 shifted copies
  __shared__ __align__(16) float sqx[C][TW];               // 4 KB (pre-biased +64)

  const int t = threadIdx.x;
  const int lane = t & 63;
  const int wave = t >> 6;     // 0..7
  const int wgrp = wave & 1;   // w-offset 64
  const int kgrp = wave >> 1;  // 0..3 : k-offset 32*kgrp
  const int col = lane & 15;
  const int quad = lane >> 4;
  const int n = blockIdx.y;
  const int w0 = blockIdx.x * TW;
  const float* xn = x + (size_t)n * C * L;

  // ---- stage fp32 x segment into bbuf-as-scratch (wave c, float4/lane) ----
  float* xf = (float*)bbuf;  // 8 ch x XFS floats = 6.4 KB <= 16 KB
  {
    const int c = wave;
    const int e = lane * 4;
    float4 v; v.x = v.y = v.z = v.w = 0.0f;
    if (lane < 48) {
      int g = w0 + e;
      if (g + 3 < L) {
        v = *(const float4*)(xn + c * L + g);
      } else {  // last w-tile tail; feeds masked windows only
        v.x = (g + 0 < L) ? xn[c * L + g + 0] : 0.0f;
        v.y = (g + 1 < L) ? xn[c * L + g + 1] : 0.0f;
        v.z = (g + 2 < L) ? xn[c * L + g + 2] : 0.0f;
        v.w = (g + 3 < L) ? xn[c * L + g + 3] : 0.0f;
      }
    }
    if (lane < 50) *(float4*)&xf[c * XFS + e] = v;   // lanes 48,49 zero-pad tail
  }
  __syncthreads();

  // ---- build 8 shifted bf16 copies (wave c; r=lane>>3; 12 dwords/lane) ----
  {
    const int cb = wave;
    const int rb = lane >> 3;         // 0..7
    const int c8 = lane & 7;
    const float* xr = xf + cb * XFS;
#pragma unroll
    for (int j = 0; j < 12; ++j) {
      int i = (c8 + j * 8) * 2;       // 0..190 even
      *(unsigned int*)&xcop[cb][rb][i] = pkbf(xr[i + rb], xr[i + rb + 1]);
    }
  }
  // ---- sliding-window fp32 sqx (+64 bias = sum(z^2)): wave c, 2 w/lane ----
  {
    const int c = wave, wl = lane * 2;
    const float* xr = xf + c * XFS;
    float p0 = 0.f, p1 = 0.f, p2 = 0.f, p3 = 0.f;
#pragma unroll
    for (int si = 0; si < S; si += 4) {
      float v0 = xr[wl + si], v1 = xr[wl + si + 1], v2 = xr[wl + si + 2], v3 = xr[wl + si + 3];
      p0 = fmaf(v0, v0, p0); p1 = fmaf(v1, v1, p1);
      p2 = fmaf(v2, v2, p2); p3 = fmaf(v3, v3, p3);
    }
    float s0 = 64.0f + (p0 + p1) + (p2 + p3);
    sqx[c][wl] = s0;
    float a = xr[wl + S], b = xr[wl];
    sqx[c][wl + 1] = s0 + a * a - b * b;
  }
  __syncthreads();  // xf dead -> bbuf free for B

  // ---- B channel 0: 16 KB via 2 full-wave gll16 per thread ----
#pragma unroll
  for (int i = 0; i < 2; ++i)
    gll16(shzB + i * 4096 + t * 8, &bbuf[i * 4096 + wave * 512]);

  const f32x4 z4 = {0.0f, 0.0f, 0.0f, 0.0f};
  f32x4 dsum[4][2];
#pragma unroll
  for (int a = 0; a < 4; ++a)
#pragma unroll
    for (int b = 0; b < 2; ++b) dsum[a][b] = z4;

  const int r8 = col & 7;
  const int abase = wgrp * 64 + (col - r8) + quad * 8;  // multiple of 8 -> b128 aligned

  for (int c = 0; c < C; ++c) {
    __syncthreads();  // READY: bbuf holds B[c] (compiler drains vmcnt here)
    bf16x8 bfr[2][2];
#pragma unroll
    for (int ks = 0; ks < 2; ++ks)
#pragma unroll
      for (int kt = 0; kt < 2; ++kt)
        bfr[ks][kt] = *(const bf16x8*)(&bbuf[((kgrp * 2 + kt) * 2 + ks) * 512 + lane * 8]);
    __syncthreads();  // DONE: all waves captured their B fragments

    if (c + 1 < C) {  // prefetch lands during the compute below
#pragma unroll
      for (int i = 0; i < 2; ++i)
        gll16(shzB + (c + 1) * 8192 + i * 4096 + t * 8, &bbuf[i * 4096 + wave * 512]);
    }

    // ---- barrier-free compute: acc = ds_read(sqx) -> MFMA -> epilogue ----
    f32x4 acc[4][2];
#pragma unroll
    for (int wt = 0; wt < 4; ++wt) {
      f32x4 sx = *(const f32x4*)&sqx[c][wgrp * 64 + wt * 16 + quad * 4];
      acc[wt][0] = sx;
      acc[wt][1] = sx;
    }
    const unsigned short* xc = &xcop[c][r8][0];
#pragma unroll
    for (int ks = 0; ks < 2; ++ks) {
#pragma unroll
      for (int wt = 0; wt < 4; ++wt) {
        bf16x8 af = *(const bf16x8*)(xc + abase + wt * 16 + ks * 32);
        acc[wt][0] = __builtin_amdgcn_mfma_f32_16x16x32_bf16(af, bfr[ks][0], acc[wt][0], 0, 0, 0);
        acc[wt][1] = __builtin_amdgcn_mfma_f32_16x16x32_bf16(af, bfr[ks][1], acc[wt][1], 0, 0, 0);
      }
    }
#pragma unroll
    for (int wt = 0; wt < 4; ++wt)
#pragma unroll
      for (int kt = 0; kt < 2; ++kt)
#pragma unroll
        for (int i = 0; i < 4; ++i)
          dsum[wt][kt][i] += __builtin_amdgcn_sqrtf(fmaxf(acc[wt][kt][i], 0.0f));
  }

  // min over w (regs -> quad shuffles), one atomicMin per k
  const float INF = __int_as_float(0x7F800000);
  int wbase = w0 + wgrp * 64;
#pragma unroll
  for (int kt = 0; kt < 2; ++kt) {
    float mv = INF;
#pragma unroll
    for (int wt = 0; wt < 4; ++wt)
#pragma unroll
      for (int i = 0; i < 4; ++i) {
        int w = wbase + wt * 16 + quad * 4 + i;
        mv = (w < W) ? fminf(mv, dsum[wt][kt][i]) : mv;
      }
    mv = fminf(mv, __shfl_xor(mv, 16));
    mv = fminf(mv, __shfl_xor(mv, 32));
    if (quad == 0)
      atomicMin(&out[n * K + kgrp * 32 + kt * 16 + col], __float_as_int(mv));
  }
}

extern "C" void kernel_launch(void* const* d_in, const int* in_sizes, int n_in,
                              void* d_out, int out_size, void* d_ws, size_t ws_size,
                              hipStream_t stream) {
  const float* x = (const float*)d_in[0];    // (64, 8, 2048) fp32
  const float* sh = (const float*)d_in[1];   // (8, 128, 64) fp32
  float* out = (float*)d_out;                // (64, 1, 128) fp32
  unsigned short* shzB = (unsigned short*)d_ws;  // 128 KB bf16 B-frag layout (scaled -2)

  prep_kernel<<<256, 256, 0, stream>>>(sh, shzB, out);
  main_kernel<<<dim3(NTW, NB), 512, 0, stream>>>(x, shzB, (int*)out);
}